// Round 13
// baseline (216.082 us; speedup 1.0000x reference)
//
#include <hip/hip_runtime.h>
#include <hip/hip_fp16.h>
#include <math.h>

#define NEG_SLOPE 0.2f

__device__ __forceinline__ float sigm(float x) { return 1.0f / (1.0f + __expf(-x)); }
__device__ __forceinline__ float tanh_fast(float x) {
    float xc = fminf(fmaxf(x, -15.0f), 15.0f);
    float e2 = __expf(2.0f * xc);
    return (e2 - 1.0f) / (e2 + 1.0f);
}
__device__ __forceinline__ float lrelu(float x) { return (x > 0.0f) ? x : NEG_SLOPE * x; }

typedef _Float16 h2v __attribute__((ext_vector_type(2)));
__device__ __forceinline__ float fdot2h(h2v a, h2v b, float c) {
#if __has_builtin(__builtin_amdgcn_fdot2)
    return __builtin_amdgcn_fdot2(a, b, c, false);
#else
    return (float)a[0] * (float)b[0] + (float)a[1] * (float)b[1] + c;
#endif
}

// dot over 8 fp16 dims held as uint4 (4 x v_dot2)
__device__ __forceinline__ float dot16(const uint4& w, const uint4& h, float acc) {
    const h2v* wp = reinterpret_cast<const h2v*>(&w);
    const h2v* hp = reinterpret_cast<const h2v*>(&h);
    acc = fdot2h(wp[0], hp[0], acc);
    acc = fdot2h(wp[1], hp[1], acc);
    acc = fdot2h(wp[2], hp[2], acc);
    acc = fdot2h(wp[3], hp[3], acc);
    return acc;
}

// ---------------- K0: zero deg ----------------
__global__ void k_zero(int* __restrict__ deg, int N) {
    int i = blockIdx.x * 256 + threadIdx.x;
    if (i < N) deg[i] = 0;
}

// ---------------- K1: histogram of dst ----------------
__global__ void k_hist(const int* __restrict__ dst, int* __restrict__ deg, int E) {
    int e = blockIdx.x * 256 + threadIdx.x;
    if (e < E) atomicAdd(deg + dst[e], 1);
}

// ---------------- scan (3 kernels, multi-block) ----------------
__global__ __launch_bounds__(256) void k_scan1(const int* __restrict__ deg,
                                               int* __restrict__ blksum, int N) {
    __shared__ int s[256];
    int tid = threadIdx.x;
    int i = blockIdx.x * 256 + tid;
    int v = (i < N) ? deg[i] : 0;
    s[tid] = v;
    __syncthreads();
    #pragma unroll
    for (int off = 128; off > 0; off >>= 1) {
        if (tid < off) s[tid] += s[tid + off];
        __syncthreads();
    }
    if (tid == 0) blksum[blockIdx.x] = s[0];
}

__global__ __launch_bounds__(256) void k_scan2(const int* __restrict__ blksum,
                                               int* __restrict__ blkoff, int nb) {
    __shared__ int s[256];
    int tid = threadIdx.x;
    int v = (tid < nb) ? blksum[tid] : 0;
    s[tid] = v;
    __syncthreads();
    for (int off = 1; off < 256; off <<= 1) {
        int t = (tid >= off) ? s[tid - off] : 0;
        __syncthreads();
        s[tid] += t;
        __syncthreads();
    }
    if (tid < nb) blkoff[tid] = s[tid] - v;   // exclusive
}

__global__ __launch_bounds__(256) void k_scan3(const int* __restrict__ deg,
                                               const int* __restrict__ blkoff,
                                               int* __restrict__ rowptr,
                                               int* __restrict__ cursor, int N, int E) {
    __shared__ int s[256];
    int tid = threadIdx.x;
    int i = blockIdx.x * 256 + tid;
    int v = (i < N) ? deg[i] : 0;
    s[tid] = v;
    __syncthreads();
    for (int off = 1; off < 256; off <<= 1) {
        int t = (tid >= off) ? s[tid - off] : 0;
        __syncthreads();
        s[tid] += t;
        __syncthreads();
    }
    int excl = s[tid] - v + blkoff[blockIdx.x];
    if (i < N) { rowptr[i] = excl; cursor[i] = excl; }
    if (i == N - 1) rowptr[N] = E;
}

// ---------------- K3: scatter edges into CSR (by dst) ----------------
__global__ void k_scatter(const int* __restrict__ src, const int* __restrict__ dst,
                          int* __restrict__ cursor, int* __restrict__ csr_src, int E) {
    int e = blockIdx.x * 256 + threadIdx.x;
    if (e < E) {
        int pos = atomicAdd(cursor + dst[e], 1);
        csr_src[pos] = src[e];
    }
}

// ---------------- K4a: wa_src[k][h] ----------------
__global__ void k_pre(const float* __restrict__ W_gat, const float* __restrict__ a_src,
                      const float* __restrict__ a_dst, float* __restrict__ wa) {
    int tid = threadIdx.x;          // tid = k*8 + h
    int k = tid >> 3, h = tid & 7;
    float s1 = 0.0f, s2 = 0.0f;
    for (int c = 0; c < 32; ++c) {
        float wv = W_gat[k * 256 + h * 32 + c];
        s1 += wv * a_src[h * 32 + c];
        s2 += wv * a_dst[h * 32 + c];
    }
    wa[tid] = s1;
    wa[256 + tid] = s2;
}

// ---------------- K4b: asrc/adst = x @ wa ----------------
__global__ __launch_bounds__(256) void k_att(const float* __restrict__ x,
                                             const float* __restrict__ wa,
                                             float* __restrict__ asrc,
                                             float* __restrict__ adst) {
    __shared__ float xs[32 * 33];
    __shared__ float was[256], wad[256];
    int tid = threadIdx.x;
    int n0 = blockIdx.x * 32;
    for (int i = tid; i < 1024; i += 256) {
        int nl = i >> 5, k = i & 31;
        xs[nl * 33 + k] = x[(size_t)(n0 + nl) * 32 + k];
    }
    was[tid] = wa[tid];
    wad[tid] = wa[256 + tid];
    __syncthreads();
    int nl = tid >> 3, h = tid & 7;
    float s1 = 0.0f, s2 = 0.0f;
    #pragma unroll
    for (int k = 0; k < 32; ++k) {
        float xv = xs[nl * 33 + k];
        s1 += xv * was[k * 8 + h];
        s2 += xv * wad[k * 8 + h];
    }
    asrc[(size_t)(n0 + nl) * 8 + h] = s1;
    adst[(size_t)(n0 + nl) * 8 + h] = s2;
}

// ---------------- K5: GAT gather, 8-deep MLP chunks ----------------
__global__ __launch_bounds__(256) void k_gat(
    const int* __restrict__ rowptr, const int* __restrict__ csr_src,
    const float* __restrict__ asrc, const float* __restrict__ adst,
    const float* __restrict__ x, float* __restrict__ z, int N) {
    int w = (blockIdx.x * 256 + threadIdx.x) >> 6;
    int lane = threadIdx.x & 63;
    if (w >= N) return;
    int r0 = rowptr[w], r1 = rowptr[w + 1];
    int h = lane >> 3, kq = lane & 7;
    float ad = adst[w * 8 + h];
    float4 acc = make_float4(0.0f, 0.0f, 0.0f, 0.0f);
    float den = 0.0f;
    const float4* x4 = (const float4*)x;
    for (int i = r0; i < r1; i += 8) {
        int rem = r1 - i;
        int s0 = csr_src[i];
        int s1 = (rem > 1) ? csr_src[i + 1] : s0;
        int s2 = (rem > 2) ? csr_src[i + 2] : s0;
        int s3 = (rem > 3) ? csr_src[i + 3] : s0;
        int s4 = (rem > 4) ? csr_src[i + 4] : s0;
        int s5 = (rem > 5) ? csr_src[i + 5] : s0;
        int s6 = (rem > 6) ? csr_src[i + 6] : s0;
        int s7 = (rem > 7) ? csr_src[i + 7] : s0;
        float a0 = asrc[s0 * 8 + h], a1 = asrc[s1 * 8 + h];
        float a2 = asrc[s2 * 8 + h], a3 = asrc[s3 * 8 + h];
        float a4 = asrc[s4 * 8 + h], a5 = asrc[s5 * 8 + h];
        float a6 = asrc[s6 * 8 + h], a7 = asrc[s7 * 8 + h];
        float4 v0 = x4[(size_t)s0 * 8 + kq], v1 = x4[(size_t)s1 * 8 + kq];
        float4 v2 = x4[(size_t)s2 * 8 + kq], v3 = x4[(size_t)s3 * 8 + kq];
        float4 v4 = x4[(size_t)s4 * 8 + kq], v5 = x4[(size_t)s5 * 8 + kq];
        float4 v6 = x4[(size_t)s6 * 8 + kq], v7 = x4[(size_t)s7 * 8 + kq];
        float e0 = __expf(lrelu(a0 + ad));
        float e1 = (rem > 1) ? __expf(lrelu(a1 + ad)) : 0.0f;
        float e2 = (rem > 2) ? __expf(lrelu(a2 + ad)) : 0.0f;
        float e3 = (rem > 3) ? __expf(lrelu(a3 + ad)) : 0.0f;
        float e4 = (rem > 4) ? __expf(lrelu(a4 + ad)) : 0.0f;
        float e5 = (rem > 5) ? __expf(lrelu(a5 + ad)) : 0.0f;
        float e6 = (rem > 6) ? __expf(lrelu(a6 + ad)) : 0.0f;
        float e7 = (rem > 7) ? __expf(lrelu(a7 + ad)) : 0.0f;
        acc.x += e0 * v0.x + e1 * v1.x + e2 * v2.x + e3 * v3.x
               + e4 * v4.x + e5 * v5.x + e6 * v6.x + e7 * v7.x;
        acc.y += e0 * v0.y + e1 * v1.y + e2 * v2.y + e3 * v3.y
               + e4 * v4.y + e5 * v5.y + e6 * v6.y + e7 * v7.y;
        acc.z += e0 * v0.z + e1 * v1.z + e2 * v2.z + e3 * v3.z
               + e4 * v4.z + e5 * v5.z + e6 * v6.z + e7 * v7.z;
        acc.w += e0 * v0.w + e1 * v1.w + e2 * v2.w + e3 * v3.w
               + e4 * v4.w + e5 * v5.w + e6 * v6.w + e7 * v7.w;
        den += ((e0 + e1) + (e2 + e3)) + ((e4 + e5) + (e6 + e7));
    }
    float inv = 1.0f / fmaxf(den, 1e-16f);
    float4 r = make_float4(acc.x * inv, acc.y * inv, acc.z * inv, acc.w * inv);
    ((float4*)z)[(size_t)w * 64 + lane] = r;
}

// ---------------- K5b: gatT[b][c][node] = z[node,:] @ M[:,c] + b_gat[c] ----------------
__global__ __launch_bounds__(256) void k_zw(
    const float* __restrict__ z, const float* __restrict__ W_gat,
    const float* __restrict__ b_gat, float* __restrict__ gatT, int N, int n_node) {
    int gw = (blockIdx.x * 256 + threadIdx.x) >> 6;  // 0..7999
    int lane = threadIdx.x & 63;
    int chalf = gw & 1;
    int nset = gw >> 1;                               // 0..3999
    int c = chalf * 16 + (lane & 15);
    int sl = lane >> 4;
    float wcol[64];
    #pragma unroll
    for (int i = 0; i < 64; ++i) {
        int k = i & 31, hh = sl * 2 + (i >> 5);
        wcol[i] = 0.125f * W_gat[k * 256 + hh * 32 + c];
    }
    float bg = b_gat[c];
    const float4* z4 = (const float4*)z;
    #pragma unroll 2
    for (int it = 0; it < 8; ++it) {
        int n = nset * 8 + it;   // always < N (grid covers exactly N/8 nsets)
        float p = 0.0f;
        #pragma unroll
        for (int k4 = 0; k4 < 16; ++k4) {
            float4 zv = z4[(size_t)n * 64 + sl * 16 + k4];
            p += zv.x * wcol[4 * k4] + zv.y * wcol[4 * k4 + 1]
               + zv.z * wcol[4 * k4 + 2] + zv.w * wcol[4 * k4 + 3];
        }
        p += __shfl_xor(p, 16, 64);
        p += __shfl_xor(p, 32, 64);
        if (lane < 16) {
            int b = n / n_node, kk = n - b * n_node;
            gatT[((size_t)b * 32 + c) * n_node + kk] = p + bg;
        }
    }
}

// ---------------- K6a: transpose W_ih1 [128][n_node] -> Wt [n_node][128] ----------------
__global__ __launch_bounds__(256) void k_wt(const float* __restrict__ W,
                                            float* __restrict__ Wt, int n_node) {
    __shared__ float tle[32][33];
    int kt = blockIdx.x & 31;
    int gt = blockIdx.x >> 5;
    int tid = threadIdx.x;
    for (int i = tid; i < 1024; i += 256) {
        int gl = i >> 5, kl = i & 31;
        int g = gt * 32 + gl, k = kt * 32 + kl;
        tle[gl][kl] = (k < n_node) ? W[(size_t)g * n_node + k] : 0.0f;
    }
    __syncthreads();
    for (int i = tid; i < 1024; i += 256) {
        int kl = i >> 5, gl = i & 31;
        int k = kt * 32 + kl, g = gt * 32 + gl;
        if (k < n_node) Wt[(size_t)k * 128 + g] = tle[gl][kl];
    }
}

// ---------------- K6c: pack LSTM weights, full-row pair layout ----------------
// k_lstm thread t (0..255): unit u = t>>1, half ht = t&1; owns rows
//   r(p) = ht*256 + p*128 + u, p in {0,1}  (ht=0: {i,f} rows; ht=1: {g,o} rows)
__global__ __launch_bounds__(256) void k_pack2(
    const float* __restrict__ W_hh2, const float* __restrict__ W_ih2,
    const float* __restrict__ W_hh1,
    uint4* __restrict__ wc2p, uint4* __restrict__ wi2p, uint4* __restrict__ w1p) {
    int i = blockIdx.x * 256 + threadIdx.x;
    __align__(16) _Float16 tmp[8];
    if (i < 8192) {
        int jj = i >> 8, t = i & 255;
        int p = jj >> 4, j = jj & 15;
        int r = (t & 1) * 256 + p * 128 + (t >> 1);
        const float* s = W_hh2 + (size_t)r * 128 + j * 8;
        #pragma unroll
        for (int k = 0; k < 8; ++k) tmp[k] = (_Float16)s[k];
        wc2p[jj * 256 + t] = *(const uint4*)tmp;
    } else if (i < 10240) {
        int ii = i - 8192;
        int jj = ii >> 8, t = ii & 255;
        int p = jj >> 2, j = jj & 3;
        int r = (t & 1) * 256 + p * 128 + (t >> 1);
        const float* s = W_ih2 + (size_t)r * 32 + j * 8;
        #pragma unroll
        for (int k = 0; k < 8; ++k) tmp[k] = (_Float16)s[k];
        wi2p[jj * 256 + t] = *(const uint4*)tmp;
    } else if (i < 10752) {
        int ii = i - 10240;
        int jj = ii >> 6, l = ii & 63;
        int p = jj >> 2, j = jj & 3;
        int r = p * 64 + l;
        const float* s = W_hh1 + (size_t)r * 32 + j * 8;
        #pragma unroll
        for (int k = 0; k < 8; ++k) tmp[k] = (_Float16)s[k];
        w1p[jj * 64 + l] = *(const uint4*)tmp;
    }
}

// ---------------- K6b: P1[t,b,g] = bias + dot(Wt[:, g], gatT[b][t][:]) ----------------
__global__ __launch_bounds__(256) void k_p1(
    const float* __restrict__ gatT, const float* __restrict__ Wt,
    const float* __restrict__ b_ih1, const float* __restrict__ b_hh1,
    float* __restrict__ P1, int n_node, int B) {
    __shared__ __align__(16) float Arow[2][1024];
    __shared__ __align__(16) float part[4][2][128];
    int blk = blockIdx.x;
    int b = blk >> 4;
    int tq = blk & 15;
    int tid = threadIdx.x;
    const float* A0 = gatT + ((size_t)b * 32 + tq * 2) * n_node;
    #pragma unroll
    for (int r = 0; r < 2; ++r)
        for (int i = tid; i < n_node; i += 256)
            Arow[r][i] = A0[(size_t)r * n_node + i];
    __syncthreads();

    int g4 = tid & 31;
    int tloc = (tid >> 5) & 1;
    int ks = tid >> 6;
    int kq = n_node >> 2;            // 250
    int k0 = ks * kq;
    const float4* Wt4 = (const float4*)Wt;
    float4 acc = make_float4(0.0f, 0.0f, 0.0f, 0.0f);
    #pragma unroll 4
    for (int k = 0; k < kq; ++k) {
        float4 w = Wt4[(size_t)(k0 + k) * 32 + g4];
        float a = Arow[tloc][k0 + k];
        acc.x += w.x * a; acc.y += w.y * a;
        acc.z += w.z * a; acc.w += w.w * a;
    }
    *(float4*)&part[ks][tloc][g4 * 4] = acc;
    __syncthreads();

    int tl = tid >> 7, g = tid & 127;
    float s = part[0][tl][g] + part[1][tl][g] + part[2][tl][g] + part[3][tl][g]
            + b_ih1[g] + b_hh1[g];
    int t = tq * 2 + tl;
    P1[((size_t)t * B + b) * 128 + g] = s;
}

// ---------------- K7: pipelined LSTM1 || LSTM2, 4-wave full-row, LDS weights ----------------
// R12 diagnosis: VGPR=124 < needed ~180 => W_hh2 regs reloaded from L2 every
// step = 192KB/CU/step @ ~56B/cy = ~3430cy/step (matches measured 3480).
// Fix: W_hh2 fp16 staged ONCE into LDS (128KB; total 148KB < 160KB, 1 blk/CU
// is fine at 32 blocks). Inner loop reads wlds[j*256+t] (lane stride 16B =
// canonical conflict-free b128): 128KB/step @ 128B/cy = ~1024cy. wi/w1 stay
// in registers (live set now ~100 < previous 124 grant).
__global__ __launch_bounds__(256, 1) void k_lstm(
    const float* __restrict__ P1, const uint4* __restrict__ wc2p,
    const uint4* __restrict__ wi2p, const uint4* __restrict__ w1p,
    const float* __restrict__ b_ih2, const float* __restrict__ b_hh2,
    float* __restrict__ h2finT, int B, int T) {
    __shared__ uint4 wlds[32 * 256];                 // 128KB fp16 W_hh2
    __shared__ __align__(16) float P1s[32][128];     // 16KB
    __shared__ __align__(16) __half h1buf[2][32];    // fp16 L1 state, dbuf
    __shared__ __align__(16) __half h2buf[2][128];   // fp16 L2 state, dbuf
    int t = threadIdx.x, b = blockIdx.x;
    int u = t >> 1, ht = t & 1;

    // stage P1
    for (int i = t; i < 1024; i += 256) {
        int tt = i >> 5, c4 = i & 31;
        ((float4*)P1s[tt])[c4] = ((const float4*)(P1 + ((size_t)tt * B + b) * 128))[c4];
    }
    // stage W_hh2 into LDS (coalesced 16B/lane loads, linear ds_write)
    #pragma unroll
    for (int j = 0; j < 32; ++j) wlds[j * 256 + t] = wc2p[j * 256 + t];
    // small weights in registers
    uint4 wi[8];
    #pragma unroll
    for (int j = 0; j < 8; ++j) wi[j] = wi2p[j * 256 + t];
    uint4 w1[8];
    if (t < 64) {
        #pragma unroll
        for (int j = 0; j < 8; ++j) w1[j] = w1p[j * 64 + t];
    }
    int r0 = ht * 256 + u;            // row p=0
    int r1 = ht * 256 + 128 + u;      // row p=1
    float bias0 = b_ih2[r0] + b_hh2[r0];
    float bias1 = b_ih2[r1] + b_hh2[r1];

    // init state
    if (t < 32) h1buf[0][t] = __float2half(0.0f);
    if (t < 128) h2buf[0][t] = __float2half(0.0f);
    float c1 = 0.0f, c2 = 0.0f;
    __syncthreads();

    for (int s = 0; s <= T; ++s) {
        // shared h1 read: h1buf[s&1] = h1[s-1] (zeros at s=0)
        const uint4* h1q = (const uint4*)h1buf[s & 1];
        uint4 hv0 = h1q[0], hv1 = h1q[1], hv2 = h1q[2], hv3 = h1q[3];

        // ---- LSTM2 step t2 = s-1 (all threads) ----
        if (s >= 1) {
            int t2 = s - 1;
            const uint4* hb = (const uint4*)h2buf[t2 & 1];
            // input projection (fp16 dot2): rows p=0,1
            float p0a, p0b, p1a, p1b;
            p0a = dot16(wi[0], hv0, 0.0f); p0b = dot16(wi[1], hv1, 0.0f);
            p0a = dot16(wi[2], hv2, p0a);  p0b = dot16(wi[3], hv3, p0b);
            p1a = dot16(wi[4], hv0, 0.0f); p1b = dot16(wi[5], hv1, 0.0f);
            p1a = dot16(wi[6], hv2, p1a);  p1b = dot16(wi[7], hv3, p1b);
            // recurrent 128-dot: weights streamed from LDS
            #pragma unroll
            for (int c = 0; c < 4; ++c) {
                uint4 h0 = hb[c * 4], h1_ = hb[c * 4 + 1];
                uint4 h2_ = hb[c * 4 + 2], h3 = hb[c * 4 + 3];
                uint4 wA0 = wlds[(c * 4 + 0) * 256 + t];
                uint4 wA1 = wlds[(c * 4 + 1) * 256 + t];
                uint4 wA2 = wlds[(c * 4 + 2) * 256 + t];
                uint4 wA3 = wlds[(c * 4 + 3) * 256 + t];
                uint4 wB0 = wlds[(16 + c * 4 + 0) * 256 + t];
                uint4 wB1 = wlds[(16 + c * 4 + 1) * 256 + t];
                uint4 wB2 = wlds[(16 + c * 4 + 2) * 256 + t];
                uint4 wB3 = wlds[(16 + c * 4 + 3) * 256 + t];
                p0a = dot16(wA0, h0, p0a);
                p0b = dot16(wA1, h1_, p0b);
                p0a = dot16(wA2, h2_, p0a);
                p0b = dot16(wA3, h3, p0b);
                p1a = dot16(wB0, h0, p1a);
                p1b = dot16(wB1, h1_, p1b);
                p1a = dot16(wB2, h2_, p1a);
                p1b = dot16(wB3, h3, p1b);
            }
            float s0 = p0a + p0b + bias0;   // ht=0: gate i | ht=1: gate g
            float s1 = p1a + p1b + bias1;   // ht=0: gate f | ht=1: gate o
            float o0 = __shfl_xor(s0, 1, 64);
            float o1 = __shfl_xor(s1, 1, 64);
            float gi = (ht == 0) ? s0 : o0;
            float gf = (ht == 0) ? s1 : o1;
            float gg = (ht == 0) ? o0 : s0;
            float go = (ht == 0) ? o1 : s1;
            c2 = sigm(gf) * c2 + sigm(gi) * tanh_fast(gg);
            float h = sigm(go) * tanh_fast(c2);
            if (ht == 0) {
                h2buf[(t2 + 1) & 1][u] = __float2half(h);
                if (t2 == T - 1) h2finT[u * 32 + b] = h;
            }
        }
        // ---- LSTM1 step s (wave 0 only) ----
        if (t < 64 && s < T) {
            float aA = P1s[s][t];
            float aB = P1s[s][64 + t];
            aA = dot16(w1[0], hv0, aA); aA = dot16(w1[1], hv1, aA);
            aA = dot16(w1[2], hv2, aA); aA = dot16(w1[3], hv3, aA);
            aB = dot16(w1[4], hv0, aB); aB = dot16(w1[5], hv1, aB);
            aB = dot16(w1[6], hv2, aB); aB = dot16(w1[7], hv3, aB);
            float oA = __shfl_xor(aA, 32, 64);
            float oB = __shfl_xor(aB, 32, 64);
            float gi = (t < 32) ? aA : oA;
            float gf = (t < 32) ? oA : aA;
            float gg = (t < 32) ? aB : oB;
            float go = (t < 32) ? oB : aB;
            c1 = sigm(gf) * c1 + sigm(gi) * tanh_fast(gg);
            float h = sigm(go) * tanh_fast(c1);
            if (t < 32) h1buf[(s + 1) & 1][t] = __float2half(h);
        }
        __syncthreads();
    }
}

// ---------------- K8: final linear from h2finT ----------------
__global__ __launch_bounds__(256) void k_fin(
    const float* __restrict__ h2finT, const float* __restrict__ W_lin,
    const float* __restrict__ b_lin, float* __restrict__ out, int n_node, int B) {
    __shared__ __align__(16) float hs[128];
    int b = blockIdx.x >> 3;
    int kc = blockIdx.x & 7;
    int tid = threadIdx.x;
    if (tid < 128) hs[tid] = h2finT[tid * 32 + b];
    __syncthreads();
    int outdim = n_node * 2;
    int kk = kc * 256 + tid;
    if (kk < outdim) {
        float acc = b_lin[kk];
        const float4* W4 = (const float4*)(W_lin + (size_t)kk * 128);
        const float4* h4 = (const float4*)hs;
        #pragma unroll 8
        for (int j = 0; j < 32; ++j) {
            float4 w = W4[j], h = h4[j];
            acc += w.x * h.x + w.y * h.y + w.z * h.z + w.w * h.w;
        }
        out[(size_t)b * outdim + kk] = acc;
    }
}

extern "C" void kernel_launch(void* const* d_in, const int* in_sizes, int n_in,
                              void* d_out, int out_size, void* d_ws, size_t ws_size,
                              hipStream_t stream) {
    const float* x     = (const float*)d_in[0];
    const int*   src   = (const int*)d_in[1];
    const int*   dst   = (const int*)d_in[2];
    const float* W_gat = (const float*)d_in[4];
    const float* a_src = (const float*)d_in[5];
    const float* a_dst = (const float*)d_in[6];
    const float* b_gat = (const float*)d_in[7];
    const float* W_ih1 = (const float*)d_in[8];
    const float* W_hh1 = (const float*)d_in[9];
    const float* b_ih1 = (const float*)d_in[10];
    const float* b_hh1 = (const float*)d_in[11];
    const float* W_ih2 = (const float*)d_in[12];
    const float* W_hh2 = (const float*)d_in[13];
    const float* b_ih2 = (const float*)d_in[14];
    const float* b_hh2 = (const float*)d_in[15];
    const float* W_lin = (const float*)d_in[16];
    const float* b_lin = (const float*)d_in[17];

    int N = in_sizes[0] / 32;          // 32000
    int E = in_sizes[1];               // 384000
    int n_node = in_sizes[8] / 128;    // 1000
    int B = N / n_node;                // 32
    int T = 32;

    float* ws = (float*)d_ws;
    float* z      = ws;                                 // N*256
    float* asrc   = z + (size_t)N * 256;                // N*8
    float* adst   = asrc + (size_t)N * 8;               // N*8
    float* gatT   = adst + (size_t)N * 8;               // N*32
    float* P1     = gatT + (size_t)N * 32;              // T*B*128
    float* wc2f   = P1 + (size_t)T * B * 128;           // 8192 uint4 = 32768 f32
    float* wiff   = wc2f + 32768;                       // 2048 uint4 = 8192 f32
    float* w1ff   = wiff + 8192;                        // 512 uint4 = 2048 f32
    float* h2finT = w1ff + 2048;                        // 128*32
    float* wa     = h2finT + 128 * 32;                  // 512
    int* deg     = (int*)(wa + 512);                    // N
    int* cursor  = deg + N;                             // N
    int* rowptr  = cursor + N;                          // N+1
    int* csr_src = rowptr + N + 1;                      // E
    int* blksum  = csr_src + E;                         // 256
    int* blkoff  = blksum + 256;                        // 256
    float* Wt    = (float*)(((uintptr_t)(blkoff + 256) + 255) & ~(uintptr_t)255); // n_node*128

    uint4* wc2p = (uint4*)wc2f;
    uint4* wi2p = (uint4*)wiff;
    uint4* w1p  = (uint4*)w1ff;

    int nb = (N + 255) / 256;   // 125

    k_pack2<<<42, 256, 0, stream>>>(W_hh2, W_ih2, W_hh1, wc2p, wi2p, w1p);
    k_wt<<<128, 256, 0, stream>>>(W_ih1, Wt, n_node);
    k_zero<<<(N + 255) / 256, 256, 0, stream>>>(deg, N);
    k_hist<<<(E + 255) / 256, 256, 0, stream>>>(dst, deg, E);
    k_scan1<<<nb, 256, 0, stream>>>(deg, blksum, N);
    k_scan2<<<1, 256, 0, stream>>>(blksum, blkoff, nb);
    k_scan3<<<nb, 256, 0, stream>>>(deg, blkoff, rowptr, cursor, N, E);
    k_scatter<<<(E + 255) / 256, 256, 0, stream>>>(src, dst, cursor, csr_src, E);
    k_pre<<<1, 256, 0, stream>>>(W_gat, a_src, a_dst, wa);
    k_att<<<N / 32, 256, 0, stream>>>(x, wa, asrc, adst);
    k_gat<<<(N * 64 + 255) / 256, 256, 0, stream>>>(rowptr, csr_src, asrc, adst,
                                                    x, z, N);
    k_zw<<<2000, 256, 0, stream>>>(z, W_gat, b_gat, gatT, N, n_node);
    k_p1<<<B * 16, 256, 0, stream>>>(gatT, Wt, b_ih1, b_hh1, P1, n_node, B);
    k_lstm<<<B, 256, 0, stream>>>(P1, wc2p, wi2p, w1p, b_ih2, b_hh2, h2finT, B, T);
    k_fin<<<B * 8, 256, 0, stream>>>(h2finT, W_lin, b_lin, (float*)d_out, n_node, B);
}

// Round 14
// 202.186 us; speedup vs baseline: 1.0687x; 1.0687x over previous
//
#include <hip/hip_runtime.h>
#include <hip/hip_fp16.h>
#include <math.h>

#define NEG_SLOPE 0.2f

__device__ __forceinline__ float sigm(float x) { return 1.0f / (1.0f + __expf(-x)); }
__device__ __forceinline__ float tanh_fast(float x) {
    float xc = fminf(fmaxf(x, -15.0f), 15.0f);
    float e2 = __expf(2.0f * xc);
    return (e2 - 1.0f) / (e2 + 1.0f);
}
__device__ __forceinline__ float lrelu(float x) { return (x > 0.0f) ? x : NEG_SLOPE * x; }

typedef _Float16 h2v __attribute__((ext_vector_type(2)));
__device__ __forceinline__ float fdot2h(h2v a, h2v b, float c) {
#if __has_builtin(__builtin_amdgcn_fdot2)
    return __builtin_amdgcn_fdot2(a, b, c, false);
#else
    return (float)a[0] * (float)b[0] + (float)a[1] * (float)b[1] + c;
#endif
}

// dot over 8 fp16 dims held as uint4 (4 x v_dot2)
__device__ __forceinline__ float dot16(const uint4& w, const uint4& h, float acc) {
    const h2v* wp = reinterpret_cast<const h2v*>(&w);
    const h2v* hp = reinterpret_cast<const h2v*>(&h);
    acc = fdot2h(wp[0], hp[0], acc);
    acc = fdot2h(wp[1], hp[1], acc);
    acc = fdot2h(wp[2], hp[2], acc);
    acc = fdot2h(wp[3], hp[3], acc);
    return acc;
}

// ---------------- K1: histogram of dst ----------------
__global__ void k_hist(const int* __restrict__ dst, int* __restrict__ deg, int E) {
    int e = blockIdx.x * 256 + threadIdx.x;
    if (e < E) atomicAdd(deg + dst[e], 1);
}

// ---------------- scan (3 kernels, multi-block) ----------------
__global__ __launch_bounds__(256) void k_scan1(const int* __restrict__ deg,
                                               int* __restrict__ blksum, int N) {
    __shared__ int s[256];
    int tid = threadIdx.x;
    int i = blockIdx.x * 256 + tid;
    int v = (i < N) ? deg[i] : 0;
    s[tid] = v;
    __syncthreads();
    #pragma unroll
    for (int off = 128; off > 0; off >>= 1) {
        if (tid < off) s[tid] += s[tid + off];
        __syncthreads();
    }
    if (tid == 0) blksum[blockIdx.x] = s[0];
}

__global__ __launch_bounds__(256) void k_scan2(const int* __restrict__ blksum,
                                               int* __restrict__ blkoff, int nb) {
    __shared__ int s[256];
    int tid = threadIdx.x;
    int v = (tid < nb) ? blksum[tid] : 0;
    s[tid] = v;
    __syncthreads();
    for (int off = 1; off < 256; off <<= 1) {
        int t = (tid >= off) ? s[tid - off] : 0;
        __syncthreads();
        s[tid] += t;
        __syncthreads();
    }
    if (tid < nb) blkoff[tid] = s[tid] - v;   // exclusive
}

__global__ __launch_bounds__(256) void k_scan3(const int* __restrict__ deg,
                                               const int* __restrict__ blkoff,
                                               int* __restrict__ rowptr,
                                               int* __restrict__ cursor, int N, int E) {
    __shared__ int s[256];
    int tid = threadIdx.x;
    int i = blockIdx.x * 256 + tid;
    int v = (i < N) ? deg[i] : 0;
    s[tid] = v;
    __syncthreads();
    for (int off = 1; off < 256; off <<= 1) {
        int t = (tid >= off) ? s[tid - off] : 0;
        __syncthreads();
        s[tid] += t;
        __syncthreads();
    }
    int excl = s[tid] - v + blkoff[blockIdx.x];
    if (i < N) { rowptr[i] = excl; cursor[i] = excl; }
    if (i == N - 1) rowptr[N] = E;
}

// ---------------- K3: scatter edges into CSR (by dst) ----------------
__global__ void k_scatter(const int* __restrict__ src, const int* __restrict__ dst,
                          int* __restrict__ cursor, int* __restrict__ csr_src, int E) {
    int e = blockIdx.x * 256 + threadIdx.x;
    if (e < E) {
        int pos = atomicAdd(cursor + dst[e], 1);
        csr_src[pos] = src[e];
    }
}

// ---------------- K_PREP: fused {k_wt | k_pack2 | k_pre | k_zero} by block range ----------------
// blocks [0,128): transpose W_ih1 -> Wt ; [128,170): pack LSTM weights ;
// block 170: wa precompute ; [171,171+nbN): zero deg.
__global__ __launch_bounds__(256) void k_prep(
    const float* __restrict__ W_ih1, float* __restrict__ Wt, int n_node,
    const float* __restrict__ W_hh2, const float* __restrict__ W_ih2,
    const float* __restrict__ W_hh1,
    uint4* __restrict__ wc2p, uint4* __restrict__ wi2p, uint4* __restrict__ w1p,
    const float* __restrict__ W_gat, const float* __restrict__ a_src,
    const float* __restrict__ a_dst, float* __restrict__ wa,
    int* __restrict__ deg, int N) {
    int blk = blockIdx.x, tid = threadIdx.x;
    if (blk < 128) {
        // ---- transpose W_ih1 [128][n_node] -> Wt [n_node][128] ----
        __shared__ float tle[32][33];
        int kt = blk & 31;
        int gt = blk >> 5;
        for (int i = tid; i < 1024; i += 256) {
            int gl = i >> 5, kl = i & 31;
            int g = gt * 32 + gl, k = kt * 32 + kl;
            tle[gl][kl] = (k < n_node) ? W_ih1[(size_t)g * n_node + k] : 0.0f;
        }
        __syncthreads();
        for (int i = tid; i < 1024; i += 256) {
            int kl = i >> 5, gl = i & 31;
            int k = kt * 32 + kl, g = gt * 32 + gl;
            if (k < n_node) Wt[(size_t)k * 128 + g] = tle[gl][kl];
        }
    } else if (blk < 170) {
        // ---- pack LSTM weights (full-row pair layout) ----
        int i = (blk - 128) * 256 + tid;   // 0..10751
        __align__(16) _Float16 tmp[8];
        if (i < 8192) {
            int jj = i >> 8, t = i & 255;
            int p = jj >> 4, j = jj & 15;
            int r = (t & 1) * 256 + p * 128 + (t >> 1);
            const float* s = W_hh2 + (size_t)r * 128 + j * 8;
            #pragma unroll
            for (int k = 0; k < 8; ++k) tmp[k] = (_Float16)s[k];
            wc2p[jj * 256 + t] = *(const uint4*)tmp;
        } else if (i < 10240) {
            int ii = i - 8192;
            int jj = ii >> 8, t = ii & 255;
            int p = jj >> 2, j = jj & 3;
            int r = (t & 1) * 256 + p * 128 + (t >> 1);
            const float* s = W_ih2 + (size_t)r * 32 + j * 8;
            #pragma unroll
            for (int k = 0; k < 8; ++k) tmp[k] = (_Float16)s[k];
            wi2p[jj * 256 + t] = *(const uint4*)tmp;
        } else if (i < 10752) {
            int ii = i - 10240;
            int jj = ii >> 6, l = ii & 63;
            int p = jj >> 2, j = jj & 3;
            int r = p * 64 + l;
            const float* s = W_hh1 + (size_t)r * 32 + j * 8;
            #pragma unroll
            for (int k = 0; k < 8; ++k) tmp[k] = (_Float16)s[k];
            w1p[jj * 64 + l] = *(const uint4*)tmp;
        }
    } else if (blk == 170) {
        // ---- wa precompute ----
        int k = tid >> 3, h = tid & 7;
        float s1 = 0.0f, s2 = 0.0f;
        for (int c = 0; c < 32; ++c) {
            float wv = W_gat[k * 256 + h * 32 + c];
            s1 += wv * a_src[h * 32 + c];
            s2 += wv * a_dst[h * 32 + c];
        }
        wa[tid] = s1;
        wa[256 + tid] = s2;
    } else {
        // ---- zero deg ----
        int i = (blk - 171) * 256 + tid;
        if (i < N) deg[i] = 0;
    }
}

// ---------------- K4b: asrc/adst = x @ wa ----------------
__global__ __launch_bounds__(256) void k_att(const float* __restrict__ x,
                                             const float* __restrict__ wa,
                                             float* __restrict__ asrc,
                                             float* __restrict__ adst) {
    __shared__ float xs[32 * 33];
    __shared__ float was[256], wad[256];
    int tid = threadIdx.x;
    int n0 = blockIdx.x * 32;
    for (int i = tid; i < 1024; i += 256) {
        int nl = i >> 5, k = i & 31;
        xs[nl * 33 + k] = x[(size_t)(n0 + nl) * 32 + k];
    }
    was[tid] = wa[tid];
    wad[tid] = wa[256 + tid];
    __syncthreads();
    int nl = tid >> 3, h = tid & 7;
    float s1 = 0.0f, s2 = 0.0f;
    #pragma unroll
    for (int k = 0; k < 32; ++k) {
        float xv = xs[nl * 33 + k];
        s1 += xv * was[k * 8 + h];
        s2 += xv * wad[k * 8 + h];
    }
    asrc[(size_t)(n0 + nl) * 8 + h] = s1;
    adst[(size_t)(n0 + nl) * 8 + h] = s2;
}

// ---------------- K5: GAT gather, 8-deep MLP chunks ----------------
__global__ __launch_bounds__(256) void k_gat(
    const int* __restrict__ rowptr, const int* __restrict__ csr_src,
    const float* __restrict__ asrc, const float* __restrict__ adst,
    const float* __restrict__ x, float* __restrict__ z, int N) {
    int w = (blockIdx.x * 256 + threadIdx.x) >> 6;
    int lane = threadIdx.x & 63;
    if (w >= N) return;
    int r0 = rowptr[w], r1 = rowptr[w + 1];
    int h = lane >> 3, kq = lane & 7;
    float ad = adst[w * 8 + h];
    float4 acc = make_float4(0.0f, 0.0f, 0.0f, 0.0f);
    float den = 0.0f;
    const float4* x4 = (const float4*)x;
    for (int i = r0; i < r1; i += 8) {
        int rem = r1 - i;
        int s0 = csr_src[i];
        int s1 = (rem > 1) ? csr_src[i + 1] : s0;
        int s2 = (rem > 2) ? csr_src[i + 2] : s0;
        int s3 = (rem > 3) ? csr_src[i + 3] : s0;
        int s4 = (rem > 4) ? csr_src[i + 4] : s0;
        int s5 = (rem > 5) ? csr_src[i + 5] : s0;
        int s6 = (rem > 6) ? csr_src[i + 6] : s0;
        int s7 = (rem > 7) ? csr_src[i + 7] : s0;
        float a0 = asrc[s0 * 8 + h], a1 = asrc[s1 * 8 + h];
        float a2 = asrc[s2 * 8 + h], a3 = asrc[s3 * 8 + h];
        float a4 = asrc[s4 * 8 + h], a5 = asrc[s5 * 8 + h];
        float a6 = asrc[s6 * 8 + h], a7 = asrc[s7 * 8 + h];
        float4 v0 = x4[(size_t)s0 * 8 + kq], v1 = x4[(size_t)s1 * 8 + kq];
        float4 v2 = x4[(size_t)s2 * 8 + kq], v3 = x4[(size_t)s3 * 8 + kq];
        float4 v4 = x4[(size_t)s4 * 8 + kq], v5 = x4[(size_t)s5 * 8 + kq];
        float4 v6 = x4[(size_t)s6 * 8 + kq], v7 = x4[(size_t)s7 * 8 + kq];
        float e0 = __expf(lrelu(a0 + ad));
        float e1 = (rem > 1) ? __expf(lrelu(a1 + ad)) : 0.0f;
        float e2 = (rem > 2) ? __expf(lrelu(a2 + ad)) : 0.0f;
        float e3 = (rem > 3) ? __expf(lrelu(a3 + ad)) : 0.0f;
        float e4 = (rem > 4) ? __expf(lrelu(a4 + ad)) : 0.0f;
        float e5 = (rem > 5) ? __expf(lrelu(a5 + ad)) : 0.0f;
        float e6 = (rem > 6) ? __expf(lrelu(a6 + ad)) : 0.0f;
        float e7 = (rem > 7) ? __expf(lrelu(a7 + ad)) : 0.0f;
        acc.x += e0 * v0.x + e1 * v1.x + e2 * v2.x + e3 * v3.x
               + e4 * v4.x + e5 * v5.x + e6 * v6.x + e7 * v7.x;
        acc.y += e0 * v0.y + e1 * v1.y + e2 * v2.y + e3 * v3.y
               + e4 * v4.y + e5 * v5.y + e6 * v6.y + e7 * v7.y;
        acc.z += e0 * v0.z + e1 * v1.z + e2 * v2.z + e3 * v3.z
               + e4 * v4.z + e5 * v5.z + e6 * v6.z + e7 * v7.z;
        acc.w += e0 * v0.w + e1 * v1.w + e2 * v2.w + e3 * v3.w
               + e4 * v4.w + e5 * v5.w + e6 * v6.w + e7 * v7.w;
        den += ((e0 + e1) + (e2 + e3)) + ((e4 + e5) + (e6 + e7));
    }
    float inv = 1.0f / fmaxf(den, 1e-16f);
    float4 r = make_float4(acc.x * inv, acc.y * inv, acc.z * inv, acc.w * inv);
    ((float4*)z)[(size_t)w * 64 + lane] = r;
}

// ---------------- K5b: gatT[b][c][node] = z[node,:] @ M[:,c] + b_gat[c] ----------------
__global__ __launch_bounds__(256) void k_zw(
    const float* __restrict__ z, const float* __restrict__ W_gat,
    const float* __restrict__ b_gat, float* __restrict__ gatT, int N, int n_node) {
    int gw = (blockIdx.x * 256 + threadIdx.x) >> 6;  // 0..7999
    int lane = threadIdx.x & 63;
    int chalf = gw & 1;
    int nset = gw >> 1;                               // 0..3999
    int c = chalf * 16 + (lane & 15);
    int sl = lane >> 4;
    float wcol[64];
    #pragma unroll
    for (int i = 0; i < 64; ++i) {
        int k = i & 31, hh = sl * 2 + (i >> 5);
        wcol[i] = 0.125f * W_gat[k * 256 + hh * 32 + c];
    }
    float bg = b_gat[c];
    const float4* z4 = (const float4*)z;
    #pragma unroll 2
    for (int it = 0; it < 8; ++it) {
        int n = nset * 8 + it;   // always < N (grid covers exactly N/8 nsets)
        float p = 0.0f;
        #pragma unroll
        for (int k4 = 0; k4 < 16; ++k4) {
            float4 zv = z4[(size_t)n * 64 + sl * 16 + k4];
            p += zv.x * wcol[4 * k4] + zv.y * wcol[4 * k4 + 1]
               + zv.z * wcol[4 * k4 + 2] + zv.w * wcol[4 * k4 + 3];
        }
        p += __shfl_xor(p, 16, 64);
        p += __shfl_xor(p, 32, 64);
        if (lane < 16) {
            int b = n / n_node, kk = n - b * n_node;
            gatT[((size_t)b * 32 + c) * n_node + kk] = p + bg;
        }
    }
}

// ---------------- K6b: P1[t,b,g] = bias + dot(Wt[:, g], gatT[b][t][:]) ----------------
__global__ __launch_bounds__(256) void k_p1(
    const float* __restrict__ gatT, const float* __restrict__ Wt,
    const float* __restrict__ b_ih1, const float* __restrict__ b_hh1,
    float* __restrict__ P1, int n_node, int B) {
    __shared__ __align__(16) float Arow[2][1024];
    __shared__ __align__(16) float part[4][2][128];
    int blk = blockIdx.x;
    int b = blk >> 4;
    int tq = blk & 15;
    int tid = threadIdx.x;
    const float* A0 = gatT + ((size_t)b * 32 + tq * 2) * n_node;
    #pragma unroll
    for (int r = 0; r < 2; ++r)
        for (int i = tid; i < n_node; i += 256)
            Arow[r][i] = A0[(size_t)r * n_node + i];
    __syncthreads();

    int g4 = tid & 31;
    int tloc = (tid >> 5) & 1;
    int ks = tid >> 6;
    int kq = n_node >> 2;            // 250
    int k0 = ks * kq;
    const float4* Wt4 = (const float4*)Wt;
    float4 acc = make_float4(0.0f, 0.0f, 0.0f, 0.0f);
    #pragma unroll 4
    for (int k = 0; k < kq; ++k) {
        float4 w = Wt4[(size_t)(k0 + k) * 32 + g4];
        float a = Arow[tloc][k0 + k];
        acc.x += w.x * a; acc.y += w.y * a;
        acc.z += w.z * a; acc.w += w.w * a;
    }
    *(float4*)&part[ks][tloc][g4 * 4] = acc;
    __syncthreads();

    int tl = tid >> 7, g = tid & 127;
    float s = part[0][tl][g] + part[1][tl][g] + part[2][tl][g] + part[3][tl][g]
            + b_ih1[g] + b_hh1[g];
    int t = tq * 2 + tl;
    P1[((size_t)t * B + b) * 128 + g] = s;
}

// ---------------- K7: pipelined LSTM1 || LSTM2, 4-wave full-row, HYBRID weights ----------------
// R12 (all-reg, allocator evicts -> L2 refetch): 3480 cy/step = 46.5 us.
// R13 (all-LDS): 32 ds_read_b128/thread/step -> LDS-issue bound, 4100 cy = 56 us.
// Hybrid: row p=0 (16 uint4) in registers (fits the ~124-132 VGPR the
// allocator grants), row p=1 (16 uint4 = 64KB) in LDS -> per-step
// 16 LDS reads + 16 register dots, minimal L2 refetch.
__global__ __launch_bounds__(256, 1) void k_lstm(
    const float* __restrict__ P1, const uint4* __restrict__ wc2p,
    const uint4* __restrict__ wi2p, const uint4* __restrict__ w1p,
    const float* __restrict__ b_ih2, const float* __restrict__ b_hh2,
    float* __restrict__ h2finT, int B, int T) {
    __shared__ uint4 wlds[16 * 256];                 // 64KB fp16 W_hh2 rows p=1
    __shared__ __align__(16) float P1s[32][128];     // 16KB
    __shared__ __align__(16) __half h1buf[2][32];    // fp16 L1 state, dbuf
    __shared__ __align__(16) __half h2buf[2][128];   // fp16 L2 state, dbuf
    int t = threadIdx.x, b = blockIdx.x;
    int u = t >> 1, ht = t & 1;

    // stage P1
    for (int i = t; i < 1024; i += 256) {
        int tt = i >> 5, c4 = i & 31;
        ((float4*)P1s[tt])[c4] = ((const float4*)(P1 + ((size_t)tt * B + b) * 128))[c4];
    }
    // row p=0 weights -> registers; row p=1 weights -> LDS
    uint4 wc[16];
    #pragma unroll
    for (int j = 0; j < 16; ++j) wc[j] = wc2p[j * 256 + t];
    #pragma unroll
    for (int j = 0; j < 16; ++j) wlds[j * 256 + t] = wc2p[(16 + j) * 256 + t];
    uint4 wi[8];
    #pragma unroll
    for (int j = 0; j < 8; ++j) wi[j] = wi2p[j * 256 + t];
    uint4 w1[8];
    if (t < 64) {
        #pragma unroll
        for (int j = 0; j < 8; ++j) w1[j] = w1p[j * 64 + t];
    }
    int r0 = ht * 256 + u;            // row p=0
    int r1 = ht * 256 + 128 + u;      // row p=1
    float bias0 = b_ih2[r0] + b_hh2[r0];
    float bias1 = b_ih2[r1] + b_hh2[r1];

    // init state
    if (t < 32) h1buf[0][t] = __float2half(0.0f);
    if (t < 128) h2buf[0][t] = __float2half(0.0f);
    float c1 = 0.0f, c2 = 0.0f;
    __syncthreads();

    for (int s = 0; s <= T; ++s) {
        // shared h1 read: h1buf[s&1] = h1[s-1] (zeros at s=0)
        const uint4* h1q = (const uint4*)h1buf[s & 1];
        uint4 hv0 = h1q[0], hv1 = h1q[1], hv2 = h1q[2], hv3 = h1q[3];

        // ---- LSTM2 step t2 = s-1 (all threads) ----
        if (s >= 1) {
            int t2 = s - 1;
            const uint4* hb = (const uint4*)h2buf[t2 & 1];
            // input projection (fp16 dot2): rows p=0,1
            float p0a, p0b, p1a, p1b;
            p0a = dot16(wi[0], hv0, 0.0f); p0b = dot16(wi[1], hv1, 0.0f);
            p0a = dot16(wi[2], hv2, p0a);  p0b = dot16(wi[3], hv3, p0b);
            p1a = dot16(wi[4], hv0, 0.0f); p1b = dot16(wi[5], hv1, 0.0f);
            p1a = dot16(wi[6], hv2, p1a);  p1b = dot16(wi[7], hv3, p1b);
            // recurrent 128-dot: p0 from registers, p1 from LDS
            #pragma unroll
            for (int c = 0; c < 4; ++c) {
                uint4 h0 = hb[c * 4], h1_ = hb[c * 4 + 1];
                uint4 h2_ = hb[c * 4 + 2], h3 = hb[c * 4 + 3];
                uint4 wB0 = wlds[(c * 4 + 0) * 256 + t];
                uint4 wB1 = wlds[(c * 4 + 1) * 256 + t];
                uint4 wB2 = wlds[(c * 4 + 2) * 256 + t];
                uint4 wB3 = wlds[(c * 4 + 3) * 256 + t];
                p0a = dot16(wc[c * 4], h0, p0a);
                p0b = dot16(wc[c * 4 + 1], h1_, p0b);
                p0a = dot16(wc[c * 4 + 2], h2_, p0a);
                p0b = dot16(wc[c * 4 + 3], h3, p0b);
                p1a = dot16(wB0, h0, p1a);
                p1b = dot16(wB1, h1_, p1b);
                p1a = dot16(wB2, h2_, p1a);
                p1b = dot16(wB3, h3, p1b);
            }
            float s0 = p0a + p0b + bias0;   // ht=0: gate i | ht=1: gate g
            float s1 = p1a + p1b + bias1;   // ht=0: gate f | ht=1: gate o
            float o0 = __shfl_xor(s0, 1, 64);
            float o1 = __shfl_xor(s1, 1, 64);
            float gi = (ht == 0) ? s0 : o0;
            float gf = (ht == 0) ? s1 : o1;
            float gg = (ht == 0) ? o0 : s0;
            float go = (ht == 0) ? o1 : s1;
            c2 = sigm(gf) * c2 + sigm(gi) * tanh_fast(gg);
            float h = sigm(go) * tanh_fast(c2);
            if (ht == 0) {
                h2buf[(t2 + 1) & 1][u] = __float2half(h);
                if (t2 == T - 1) h2finT[u * 32 + b] = h;
            }
        }
        // ---- LSTM1 step s (wave 0 only) ----
        if (t < 64 && s < T) {
            float aA = P1s[s][t];
            float aB = P1s[s][64 + t];
            aA = dot16(w1[0], hv0, aA); aA = dot16(w1[1], hv1, aA);
            aA = dot16(w1[2], hv2, aA); aA = dot16(w1[3], hv3, aA);
            aB = dot16(w1[4], hv0, aB); aB = dot16(w1[5], hv1, aB);
            aB = dot16(w1[6], hv2, aB); aB = dot16(w1[7], hv3, aB);
            float oA = __shfl_xor(aA, 32, 64);
            float oB = __shfl_xor(aB, 32, 64);
            float gi = (t < 32) ? aA : oA;
            float gf = (t < 32) ? oA : aA;
            float gg = (t < 32) ? aB : oB;
            float go = (t < 32) ? oB : aB;
            c1 = sigm(gf) * c1 + sigm(gi) * tanh_fast(gg);
            float h = sigm(go) * tanh_fast(c1);
            if (t < 32) h1buf[(s + 1) & 1][t] = __float2half(h);
        }
        __syncthreads();
    }
}

// ---------------- K8: final linear from h2finT ----------------
__global__ __launch_bounds__(256) void k_fin(
    const float* __restrict__ h2finT, const float* __restrict__ W_lin,
    const float* __restrict__ b_lin, float* __restrict__ out, int n_node, int B) {
    __shared__ __align__(16) float hs[128];
    int b = blockIdx.x >> 3;
    int kc = blockIdx.x & 7;
    int tid = threadIdx.x;
    if (tid < 128) hs[tid] = h2finT[tid * 32 + b];
    __syncthreads();
    int outdim = n_node * 2;
    int kk = kc * 256 + tid;
    if (kk < outdim) {
        float acc = b_lin[kk];
        const float4* W4 = (const float4*)(W_lin + (size_t)kk * 128);
        const float4* h4 = (const float4*)hs;
        #pragma unroll 8
        for (int j = 0; j < 32; ++j) {
            float4 w = W4[j], h = h4[j];
            acc += w.x * h.x + w.y * h.y + w.z * h.z + w.w * h.w;
        }
        out[(size_t)b * outdim + kk] = acc;
    }
}

extern "C" void kernel_launch(void* const* d_in, const int* in_sizes, int n_in,
                              void* d_out, int out_size, void* d_ws, size_t ws_size,
                              hipStream_t stream) {
    const float* x     = (const float*)d_in[0];
    const int*   src   = (const int*)d_in[1];
    const int*   dst   = (const int*)d_in[2];
    const float* W_gat = (const float*)d_in[4];
    const float* a_src = (const float*)d_in[5];
    const float* a_dst = (const float*)d_in[6];
    const float* b_gat = (const float*)d_in[7];
    const float* W_ih1 = (const float*)d_in[8];
    const float* W_hh1 = (const float*)d_in[9];
    const float* b_ih1 = (const float*)d_in[10];
    const float* b_hh1 = (const float*)d_in[11];
    const float* W_ih2 = (const float*)d_in[12];
    const float* W_hh2 = (const float*)d_in[13];
    const float* b_ih2 = (const float*)d_in[14];
    const float* b_hh2 = (const float*)d_in[15];
    const float* W_lin = (const float*)d_in[16];
    const float* b_lin = (const float*)d_in[17];

    int N = in_sizes[0] / 32;          // 32000
    int E = in_sizes[1];               // 384000
    int n_node = in_sizes[8] / 128;    // 1000
    int B = N / n_node;                // 32
    int T = 32;

    float* ws = (float*)d_ws;
    float* z      = ws;                                 // N*256
    float* asrc   = z + (size_t)N * 256;                // N*8
    float* adst   = asrc + (size_t)N * 8;               // N*8
    float* gatT   = adst + (size_t)N * 8;               // N*32
    float* P1     = gatT + (size_t)N * 32;              // T*B*128
    float* wc2f   = P1 + (size_t)T * B * 128;           // 8192 uint4 = 32768 f32
    float* wiff   = wc2f + 32768;                       // 2048 uint4 = 8192 f32
    float* w1ff   = wiff + 8192;                        // 512 uint4 = 2048 f32
    float* h2finT = w1ff + 2048;                        // 128*32
    float* wa     = h2finT + 128 * 32;                  // 512
    int* deg     = (int*)(wa + 512);                    // N
    int* cursor  = deg + N;                             // N
    int* rowptr  = cursor + N;                          // N+1
    int* csr_src = rowptr + N + 1;                      // E
    int* blksum  = csr_src + E;                         // 256
    int* blkoff  = blksum + 256;                        // 256
    float* Wt    = (float*)(((uintptr_t)(blkoff + 256) + 255) & ~(uintptr_t)255); // n_node*128

    uint4* wc2p = (uint4*)wc2f;
    uint4* wi2p = (uint4*)wiff;
    uint4* w1p  = (uint4*)w1ff;

    int nb = (N + 255) / 256;   // 125

    k_prep<<<171 + nb, 256, 0, stream>>>(W_ih1, Wt, n_node, W_hh2, W_ih2, W_hh1,
                                         wc2p, wi2p, w1p, W_gat, a_src, a_dst,
                                         wa, deg, N);
    k_hist<<<(E + 255) / 256, 256, 0, stream>>>(dst, deg, E);
    k_scan1<<<nb, 256, 0, stream>>>(deg, blksum, N);
    k_scan2<<<1, 256, 0, stream>>>(blksum, blkoff, nb);
    k_scan3<<<nb, 256, 0, stream>>>(deg, blkoff, rowptr, cursor, N, E);
    k_scatter<<<(E + 255) / 256, 256, 0, stream>>>(src, dst, cursor, csr_src, E);
    k_att<<<N / 32, 256, 0, stream>>>(x, wa, asrc, adst);
    k_gat<<<(N * 64 + 255) / 256, 256, 0, stream>>>(rowptr, csr_src, asrc, adst,
                                                    x, z, N);
    k_zw<<<2000, 256, 0, stream>>>(z, W_gat, b_gat, gatT, N, n_node);
    k_p1<<<B * 16, 256, 0, stream>>>(gatT, Wt, b_ih1, b_hh1, P1, n_node, B);
    k_lstm<<<B, 256, 0, stream>>>(P1, wc2p, wi2p, w1p, b_ih2, b_hh2, h2finT, B, T);
    k_fin<<<B * 8, 256, 0, stream>>>(h2finT, W_lin, b_lin, (float*)d_out, n_node, B);
}

// Round 15
// 198.612 us; speedup vs baseline: 1.0880x; 1.0180x over previous
//
#include <hip/hip_runtime.h>
#include <hip/hip_fp16.h>
#include <math.h>

#define NEG_SLOPE 0.2f

__device__ __forceinline__ float sigm(float x) { return 1.0f / (1.0f + __expf(-x)); }
__device__ __forceinline__ float tanh_fast(float x) {
    float xc = fminf(fmaxf(x, -15.0f), 15.0f);
    float e2 = __expf(2.0f * xc);
    return (e2 - 1.0f) / (e2 + 1.0f);
}
__device__ __forceinline__ float lrelu(float x) { return (x > 0.0f) ? x : NEG_SLOPE * x; }

typedef _Float16 h2v __attribute__((ext_vector_type(2)));
__device__ __forceinline__ float fdot2h(h2v a, h2v b, float c) {
#if __has_builtin(__builtin_amdgcn_fdot2)
    return __builtin_amdgcn_fdot2(a, b, c, false);
#else
    return (float)a[0] * (float)b[0] + (float)a[1] * (float)b[1] + c;
#endif
}

// dot over 8 fp16 dims held as uint4 (4 x v_dot2)
__device__ __forceinline__ float dot16(const uint4& w, const uint4& h, float acc) {
    const h2v* wp = reinterpret_cast<const h2v*>(&w);
    const h2v* hp = reinterpret_cast<const h2v*>(&h);
    acc = fdot2h(wp[0], hp[0], acc);
    acc = fdot2h(wp[1], hp[1], acc);
    acc = fdot2h(wp[2], hp[2], acc);
    acc = fdot2h(wp[3], hp[3], acc);
    return acc;
}

// ---------------- K1: histogram of dst ----------------
__global__ void k_hist(const int* __restrict__ dst, int* __restrict__ deg, int E) {
    int e = blockIdx.x * 256 + threadIdx.x;
    if (e < E) atomicAdd(deg + dst[e], 1);
}

// ---------------- scan (3 kernels, multi-block) ----------------
__global__ __launch_bounds__(256) void k_scan1(const int* __restrict__ deg,
                                               int* __restrict__ blksum, int N) {
    __shared__ int s[256];
    int tid = threadIdx.x;
    int i = blockIdx.x * 256 + tid;
    int v = (i < N) ? deg[i] : 0;
    s[tid] = v;
    __syncthreads();
    #pragma unroll
    for (int off = 128; off > 0; off >>= 1) {
        if (tid < off) s[tid] += s[tid + off];
        __syncthreads();
    }
    if (tid == 0) blksum[blockIdx.x] = s[0];
}

__global__ __launch_bounds__(256) void k_scan2(const int* __restrict__ blksum,
                                               int* __restrict__ blkoff, int nb) {
    __shared__ int s[256];
    int tid = threadIdx.x;
    int v = (tid < nb) ? blksum[tid] : 0;
    s[tid] = v;
    __syncthreads();
    for (int off = 1; off < 256; off <<= 1) {
        int t = (tid >= off) ? s[tid - off] : 0;
        __syncthreads();
        s[tid] += t;
        __syncthreads();
    }
    if (tid < nb) blkoff[tid] = s[tid] - v;   // exclusive
}

__global__ __launch_bounds__(256) void k_scan3(const int* __restrict__ deg,
                                               const int* __restrict__ blkoff,
                                               int* __restrict__ rowptr,
                                               int* __restrict__ cursor, int N, int E) {
    __shared__ int s[256];
    int tid = threadIdx.x;
    int i = blockIdx.x * 256 + tid;
    int v = (i < N) ? deg[i] : 0;
    s[tid] = v;
    __syncthreads();
    for (int off = 1; off < 256; off <<= 1) {
        int t = (tid >= off) ? s[tid - off] : 0;
        __syncthreads();
        s[tid] += t;
        __syncthreads();
    }
    int excl = s[tid] - v + blkoff[blockIdx.x];
    if (i < N) { rowptr[i] = excl; cursor[i] = excl; }
    if (i == N - 1) rowptr[N] = E;
}

// ---------------- K3: scatter edges into CSR (by dst) ----------------
__global__ void k_scatter(const int* __restrict__ src, const int* __restrict__ dst,
                          int* __restrict__ cursor, int* __restrict__ csr_src, int E) {
    int e = blockIdx.x * 256 + threadIdx.x;
    if (e < E) {
        int pos = atomicAdd(cursor + dst[e], 1);
        csr_src[pos] = src[e];
    }
}

// ---------------- K_PREP: fused {k_wt | k_pack2 | k_pre | k_zero} by block range ----------------
// blocks [0,128): transpose W_ih1 -> Wt ; [128,170): pack LSTM weights ;
// block 170: wa precompute ; [171,171+nbN): zero deg.
__global__ __launch_bounds__(256) void k_prep(
    const float* __restrict__ W_ih1, float* __restrict__ Wt, int n_node,
    const float* __restrict__ W_hh2, const float* __restrict__ W_ih2,
    const float* __restrict__ W_hh1,
    uint4* __restrict__ wc2p, uint4* __restrict__ wi2p, uint4* __restrict__ w1p,
    const float* __restrict__ W_gat, const float* __restrict__ a_src,
    const float* __restrict__ a_dst, float* __restrict__ wa,
    int* __restrict__ deg, int N) {
    int blk = blockIdx.x, tid = threadIdx.x;
    if (blk < 128) {
        // ---- transpose W_ih1 [128][n_node] -> Wt [n_node][128] ----
        __shared__ float tle[32][33];
        int kt = blk & 31;
        int gt = blk >> 5;
        for (int i = tid; i < 1024; i += 256) {
            int gl = i >> 5, kl = i & 31;
            int g = gt * 32 + gl, k = kt * 32 + kl;
            tle[gl][kl] = (k < n_node) ? W_ih1[(size_t)g * n_node + k] : 0.0f;
        }
        __syncthreads();
        for (int i = tid; i < 1024; i += 256) {
            int kl = i >> 5, gl = i & 31;
            int k = kt * 32 + kl, g = gt * 32 + gl;
            if (k < n_node) Wt[(size_t)k * 128 + g] = tle[gl][kl];
        }
    } else if (blk < 170) {
        // ---- pack LSTM weights (full-row pair layout) ----
        int i = (blk - 128) * 256 + tid;   // 0..10751
        __align__(16) _Float16 tmp[8];
        if (i < 8192) {
            int jj = i >> 8, t = i & 255;
            int p = jj >> 4, j = jj & 15;
            int r = (t & 1) * 256 + p * 128 + (t >> 1);
            const float* s = W_hh2 + (size_t)r * 128 + j * 8;
            #pragma unroll
            for (int k = 0; k < 8; ++k) tmp[k] = (_Float16)s[k];
            wc2p[jj * 256 + t] = *(const uint4*)tmp;
        } else if (i < 10240) {
            int ii = i - 8192;
            int jj = ii >> 8, t = ii & 255;
            int p = jj >> 2, j = jj & 3;
            int r = (t & 1) * 256 + p * 128 + (t >> 1);
            const float* s = W_ih2 + (size_t)r * 32 + j * 8;
            #pragma unroll
            for (int k = 0; k < 8; ++k) tmp[k] = (_Float16)s[k];
            wi2p[jj * 256 + t] = *(const uint4*)tmp;
        } else if (i < 10752) {
            int ii = i - 10240;
            int jj = ii >> 6, l = ii & 63;
            int p = jj >> 2, j = jj & 3;
            int r = p * 64 + l;
            const float* s = W_hh1 + (size_t)r * 32 + j * 8;
            #pragma unroll
            for (int k = 0; k < 8; ++k) tmp[k] = (_Float16)s[k];
            w1p[jj * 64 + l] = *(const uint4*)tmp;
        }
    } else if (blk == 170) {
        // ---- wa precompute ----
        int k = tid >> 3, h = tid & 7;
        float s1 = 0.0f, s2 = 0.0f;
        for (int c = 0; c < 32; ++c) {
            float wv = W_gat[k * 256 + h * 32 + c];
            s1 += wv * a_src[h * 32 + c];
            s2 += wv * a_dst[h * 32 + c];
        }
        wa[tid] = s1;
        wa[256 + tid] = s2;
    } else {
        // ---- zero deg ----
        int i = (blk - 171) * 256 + tid;
        if (i < N) deg[i] = 0;
    }
}

// ---------------- K4b: asrc/adst = x @ wa ----------------
__global__ __launch_bounds__(256) void k_att(const float* __restrict__ x,
                                             const float* __restrict__ wa,
                                             float* __restrict__ asrc,
                                             float* __restrict__ adst) {
    __shared__ float xs[32 * 33];
    __shared__ float was[256], wad[256];
    int tid = threadIdx.x;
    int n0 = blockIdx.x * 32;
    for (int i = tid; i < 1024; i += 256) {
        int nl = i >> 5, k = i & 31;
        xs[nl * 33 + k] = x[(size_t)(n0 + nl) * 32 + k];
    }
    was[tid] = wa[tid];
    wad[tid] = wa[256 + tid];
    __syncthreads();
    int nl = tid >> 3, h = tid & 7;
    float s1 = 0.0f, s2 = 0.0f;
    #pragma unroll
    for (int k = 0; k < 32; ++k) {
        float xv = xs[nl * 33 + k];
        s1 += xv * was[k * 8 + h];
        s2 += xv * wad[k * 8 + h];
    }
    asrc[(size_t)(n0 + nl) * 8 + h] = s1;
    adst[(size_t)(n0 + nl) * 8 + h] = s2;
}

// ---------------- K5: GAT gather, 8-deep MLP chunks ----------------
__global__ __launch_bounds__(256) void k_gat(
    const int* __restrict__ rowptr, const int* __restrict__ csr_src,
    const float* __restrict__ asrc, const float* __restrict__ adst,
    const float* __restrict__ x, float* __restrict__ z, int N) {
    int w = (blockIdx.x * 256 + threadIdx.x) >> 6;
    int lane = threadIdx.x & 63;
    if (w >= N) return;
    int r0 = rowptr[w], r1 = rowptr[w + 1];
    int h = lane >> 3, kq = lane & 7;
    float ad = adst[w * 8 + h];
    float4 acc = make_float4(0.0f, 0.0f, 0.0f, 0.0f);
    float den = 0.0f;
    const float4* x4 = (const float4*)x;
    for (int i = r0; i < r1; i += 8) {
        int rem = r1 - i;
        int s0 = csr_src[i];
        int s1 = (rem > 1) ? csr_src[i + 1] : s0;
        int s2 = (rem > 2) ? csr_src[i + 2] : s0;
        int s3 = (rem > 3) ? csr_src[i + 3] : s0;
        int s4 = (rem > 4) ? csr_src[i + 4] : s0;
        int s5 = (rem > 5) ? csr_src[i + 5] : s0;
        int s6 = (rem > 6) ? csr_src[i + 6] : s0;
        int s7 = (rem > 7) ? csr_src[i + 7] : s0;
        float a0 = asrc[s0 * 8 + h], a1 = asrc[s1 * 8 + h];
        float a2 = asrc[s2 * 8 + h], a3 = asrc[s3 * 8 + h];
        float a4 = asrc[s4 * 8 + h], a5 = asrc[s5 * 8 + h];
        float a6 = asrc[s6 * 8 + h], a7 = asrc[s7 * 8 + h];
        float4 v0 = x4[(size_t)s0 * 8 + kq], v1 = x4[(size_t)s1 * 8 + kq];
        float4 v2 = x4[(size_t)s2 * 8 + kq], v3 = x4[(size_t)s3 * 8 + kq];
        float4 v4 = x4[(size_t)s4 * 8 + kq], v5 = x4[(size_t)s5 * 8 + kq];
        float4 v6 = x4[(size_t)s6 * 8 + kq], v7 = x4[(size_t)s7 * 8 + kq];
        float e0 = __expf(lrelu(a0 + ad));
        float e1 = (rem > 1) ? __expf(lrelu(a1 + ad)) : 0.0f;
        float e2 = (rem > 2) ? __expf(lrelu(a2 + ad)) : 0.0f;
        float e3 = (rem > 3) ? __expf(lrelu(a3 + ad)) : 0.0f;
        float e4 = (rem > 4) ? __expf(lrelu(a4 + ad)) : 0.0f;
        float e5 = (rem > 5) ? __expf(lrelu(a5 + ad)) : 0.0f;
        float e6 = (rem > 6) ? __expf(lrelu(a6 + ad)) : 0.0f;
        float e7 = (rem > 7) ? __expf(lrelu(a7 + ad)) : 0.0f;
        acc.x += e0 * v0.x + e1 * v1.x + e2 * v2.x + e3 * v3.x
               + e4 * v4.x + e5 * v5.x + e6 * v6.x + e7 * v7.x;
        acc.y += e0 * v0.y + e1 * v1.y + e2 * v2.y + e3 * v3.y
               + e4 * v4.y + e5 * v5.y + e6 * v6.y + e7 * v7.y;
        acc.z += e0 * v0.z + e1 * v1.z + e2 * v2.z + e3 * v3.z
               + e4 * v4.z + e5 * v5.z + e6 * v6.z + e7 * v7.z;
        acc.w += e0 * v0.w + e1 * v1.w + e2 * v2.w + e3 * v3.w
               + e4 * v4.w + e5 * v5.w + e6 * v6.w + e7 * v7.w;
        den += ((e0 + e1) + (e2 + e3)) + ((e4 + e5) + (e6 + e7));
    }
    float inv = 1.0f / fmaxf(den, 1e-16f);
    float4 r = make_float4(acc.x * inv, acc.y * inv, acc.z * inv, acc.w * inv);
    ((float4*)z)[(size_t)w * 64 + lane] = r;
}

// ---------------- K5b: gatT[b][c][node] = z[node,:] @ M[:,c] + b_gat[c] ----------------
__global__ __launch_bounds__(256) void k_zw(
    const float* __restrict__ z, const float* __restrict__ W_gat,
    const float* __restrict__ b_gat, float* __restrict__ gatT, int N, int n_node) {
    int gw = (blockIdx.x * 256 + threadIdx.x) >> 6;  // 0..7999
    int lane = threadIdx.x & 63;
    int chalf = gw & 1;
    int nset = gw >> 1;                               // 0..3999
    int c = chalf * 16 + (lane & 15);
    int sl = lane >> 4;
    float wcol[64];
    #pragma unroll
    for (int i = 0; i < 64; ++i) {
        int k = i & 31, hh = sl * 2 + (i >> 5);
        wcol[i] = 0.125f * W_gat[k * 256 + hh * 32 + c];
    }
    float bg = b_gat[c];
    const float4* z4 = (const float4*)z;
    #pragma unroll 2
    for (int it = 0; it < 8; ++it) {
        int n = nset * 8 + it;   // always < N (grid covers exactly N/8 nsets)
        float p = 0.0f;
        #pragma unroll
        for (int k4 = 0; k4 < 16; ++k4) {
            float4 zv = z4[(size_t)n * 64 + sl * 16 + k4];
            p += zv.x * wcol[4 * k4] + zv.y * wcol[4 * k4 + 1]
               + zv.z * wcol[4 * k4 + 2] + zv.w * wcol[4 * k4 + 3];
        }
        p += __shfl_xor(p, 16, 64);
        p += __shfl_xor(p, 32, 64);
        if (lane < 16) {
            int b = n / n_node, kk = n - b * n_node;
            gatT[((size_t)b * 32 + c) * n_node + kk] = p + bg;
        }
    }
}

// ---------------- K6b: P1[t,b,g] = bias + dot(Wt[:, g], gatT[b][t][:]) ----------------
__global__ __launch_bounds__(256) void k_p1(
    const float* __restrict__ gatT, const float* __restrict__ Wt,
    const float* __restrict__ b_ih1, const float* __restrict__ b_hh1,
    float* __restrict__ P1, int n_node, int B) {
    __shared__ __align__(16) float Arow[2][1024];
    __shared__ __align__(16) float part[4][2][128];
    int blk = blockIdx.x;
    int b = blk >> 4;
    int tq = blk & 15;
    int tid = threadIdx.x;
    const float* A0 = gatT + ((size_t)b * 32 + tq * 2) * n_node;
    #pragma unroll
    for (int r = 0; r < 2; ++r)
        for (int i = tid; i < n_node; i += 256)
            Arow[r][i] = A0[(size_t)r * n_node + i];
    __syncthreads();

    int g4 = tid & 31;
    int tloc = (tid >> 5) & 1;
    int ks = tid >> 6;
    int kq = n_node >> 2;            // 250
    int k0 = ks * kq;
    const float4* Wt4 = (const float4*)Wt;
    float4 acc = make_float4(0.0f, 0.0f, 0.0f, 0.0f);
    #pragma unroll 4
    for (int k = 0; k < kq; ++k) {
        float4 w = Wt4[(size_t)(k0 + k) * 32 + g4];
        float a = Arow[tloc][k0 + k];
        acc.x += w.x * a; acc.y += w.y * a;
        acc.z += w.z * a; acc.w += w.w * a;
    }
    *(float4*)&part[ks][tloc][g4 * 4] = acc;
    __syncthreads();

    int tl = tid >> 7, g = tid & 127;
    float s = part[0][tl][g] + part[1][tl][g] + part[2][tl][g] + part[3][tl][g]
            + b_ih1[g] + b_hh1[g];
    int t = tq * 2 + tl;
    P1[((size_t)t * B + b) * 128 + g] = s;
}

// ---------------- K7: pipelined LSTM1 || LSTM2, 4-wave full-row (R12-proven, 46.5us) ----------------
// Empirical placement series: all-reg(this)=46.5 < hybrid=51.4 < all-LDS=56.4.
// Compiler grants ~124 VGPR and streams weights from L2 per step; that stream
// is bandwidth-bound (~3480cy/step) and is the cheapest placement hipcc emits.
__global__ __launch_bounds__(256, 1) void k_lstm(
    const float* __restrict__ P1, const uint4* __restrict__ wc2p,
    const uint4* __restrict__ wi2p, const uint4* __restrict__ w1p,
    const float* __restrict__ b_ih2, const float* __restrict__ b_hh2,
    float* __restrict__ h2finT, int B, int T) {
    __shared__ __align__(16) float P1s[32][128];     // 16KB
    __shared__ __align__(16) __half h1buf[2][32];    // fp16 L1 state, dbuf
    __shared__ __align__(16) __half h2buf[2][128];   // fp16 L2 state, dbuf
    int t = threadIdx.x, b = blockIdx.x;
    int u = t >> 1, ht = t & 1;

    // stage P1
    for (int i = t; i < 1024; i += 256) {
        int tt = i >> 5, c4 = i & 31;
        ((float4*)P1s[tt])[c4] = ((const float4*)(P1 + ((size_t)tt * B + b) * 128))[c4];
    }
    // weights: coalesced preload
    uint4 wc[32];
    #pragma unroll
    for (int j = 0; j < 32; ++j) wc[j] = wc2p[j * 256 + t];
    uint4 wi[8];
    #pragma unroll
    for (int j = 0; j < 8; ++j) wi[j] = wi2p[j * 256 + t];
    uint4 w1[8];
    if (t < 64) {
        #pragma unroll
        for (int j = 0; j < 8; ++j) w1[j] = w1p[j * 64 + t];
    }
    int r0 = ht * 256 + u;            // row p=0
    int r1 = ht * 256 + 128 + u;      // row p=1
    float bias0 = b_ih2[r0] + b_hh2[r0];
    float bias1 = b_ih2[r1] + b_hh2[r1];

    // init state
    if (t < 32) h1buf[0][t] = __float2half(0.0f);
    if (t < 128) h2buf[0][t] = __float2half(0.0f);
    float c1 = 0.0f, c2 = 0.0f;
    __syncthreads();

    for (int s = 0; s <= T; ++s) {
        // shared h1 read: h1buf[s&1] = h1[s-1] (zeros at s=0)
        const uint4* h1q = (const uint4*)h1buf[s & 1];
        uint4 hv0 = h1q[0], hv1 = h1q[1], hv2 = h1q[2], hv3 = h1q[3];

        // ---- LSTM2 step t2 = s-1 (all threads) ----
        if (s >= 1) {
            int t2 = s - 1;
            const uint4* hb = (const uint4*)h2buf[t2 & 1];
            // input projection (fp16 dot2): rows p=0,1
            float p0a, p0b, p1a, p1b;
            p0a = dot16(wi[0], hv0, 0.0f); p0b = dot16(wi[1], hv1, 0.0f);
            p0a = dot16(wi[2], hv2, p0a);  p0b = dot16(wi[3], hv3, p0b);
            p1a = dot16(wi[4], hv0, 0.0f); p1b = dot16(wi[5], hv1, 0.0f);
            p1a = dot16(wi[6], hv2, p1a);  p1b = dot16(wi[7], hv3, p1b);
            // recurrent 128-dot, chunked h2 reads (4 uint4 live at a time)
            #pragma unroll
            for (int c = 0; c < 4; ++c) {
                uint4 h0 = hb[c * 4], h1_ = hb[c * 4 + 1];
                uint4 h2_ = hb[c * 4 + 2], h3 = hb[c * 4 + 3];
                p0a = dot16(wc[c * 4], h0, p0a);
                p0b = dot16(wc[c * 4 + 1], h1_, p0b);
                p0a = dot16(wc[c * 4 + 2], h2_, p0a);
                p0b = dot16(wc[c * 4 + 3], h3, p0b);
                p1a = dot16(wc[16 + c * 4], h0, p1a);
                p1b = dot16(wc[16 + c * 4 + 1], h1_, p1b);
                p1a = dot16(wc[16 + c * 4 + 2], h2_, p1a);
                p1b = dot16(wc[16 + c * 4 + 3], h3, p1b);
            }
            float s0 = p0a + p0b + bias0;   // ht=0: gate i | ht=1: gate g
            float s1 = p1a + p1b + bias1;   // ht=0: gate f | ht=1: gate o
            float o0 = __shfl_xor(s0, 1, 64);
            float o1 = __shfl_xor(s1, 1, 64);
            float gi = (ht == 0) ? s0 : o0;
            float gf = (ht == 0) ? s1 : o1;
            float gg = (ht == 0) ? o0 : s0;
            float go = (ht == 0) ? o1 : s1;
            c2 = sigm(gf) * c2 + sigm(gi) * tanh_fast(gg);
            float h = sigm(go) * tanh_fast(c2);
            if (ht == 0) {
                h2buf[(t2 + 1) & 1][u] = __float2half(h);
                if (t2 == T - 1) h2finT[u * 32 + b] = h;
            }
        }
        // ---- LSTM1 step s (wave 0 only) ----
        if (t < 64 && s < T) {
            float aA = P1s[s][t];
            float aB = P1s[s][64 + t];
            aA = dot16(w1[0], hv0, aA); aA = dot16(w1[1], hv1, aA);
            aA = dot16(w1[2], hv2, aA); aA = dot16(w1[3], hv3, aA);
            aB = dot16(w1[4], hv0, aB); aB = dot16(w1[5], hv1, aB);
            aB = dot16(w1[6], hv2, aB); aB = dot16(w1[7], hv3, aB);
            float oA = __shfl_xor(aA, 32, 64);
            float oB = __shfl_xor(aB, 32, 64);
            float gi = (t < 32) ? aA : oA;
            float gf = (t < 32) ? oA : aA;
            float gg = (t < 32) ? aB : oB;
            float go = (t < 32) ? oB : aB;
            c1 = sigm(gf) * c1 + sigm(gi) * tanh_fast(gg);
            float h = sigm(go) * tanh_fast(c1);
            if (t < 32) h1buf[(s + 1) & 1][t] = __float2half(h);
        }
        __syncthreads();
    }
}

// ---------------- K8: final linear from h2finT ----------------
__global__ __launch_bounds__(256) void k_fin(
    const float* __restrict__ h2finT, const float* __restrict__ W_lin,
    const float* __restrict__ b_lin, float* __restrict__ out, int n_node, int B) {
    __shared__ __align__(16) float hs[128];
    int b = blockIdx.x >> 3;
    int kc = blockIdx.x & 7;
    int tid = threadIdx.x;
    if (tid < 128) hs[tid] = h2finT[tid * 32 + b];
    __syncthreads();
    int outdim = n_node * 2;
    int kk = kc * 256 + tid;
    if (kk < outdim) {
        float acc = b_lin[kk];
        const float4* W4 = (const float4*)(W_lin + (size_t)kk * 128);
        const float4* h4 = (const float4*)hs;
        #pragma unroll 8
        for (int j = 0; j < 32; ++j) {
            float4 w = W4[j], h = h4[j];
            acc += w.x * h.x + w.y * h.y + w.z * h.z + w.w * h.w;
        }
        out[(size_t)b * outdim + kk] = acc;
    }
}

extern "C" void kernel_launch(void* const* d_in, const int* in_sizes, int n_in,
                              void* d_out, int out_size, void* d_ws, size_t ws_size,
                              hipStream_t stream) {
    const float* x     = (const float*)d_in[0];
    const int*   src   = (const int*)d_in[1];
    const int*   dst   = (const int*)d_in[2];
    const float* W_gat = (const float*)d_in[4];
    const float* a_src = (const float*)d_in[5];
    const float* a_dst = (const float*)d_in[6];
    const float* b_gat = (const float*)d_in[7];
    const float* W_ih1 = (const float*)d_in[8];
    const float* W_hh1 = (const float*)d_in[9];
    const float* b_ih1 = (const float*)d_in[10];
    const float* b_hh1 = (const float*)d_in[11];
    const float* W_ih2 = (const float*)d_in[12];
    const float* W_hh2 = (const float*)d_in[13];
    const float* b_ih2 = (const float*)d_in[14];
    const float* b_hh2 = (const float*)d_in[15];
    const float* W_lin = (const float*)d_in[16];
    const float* b_lin = (const float*)d_in[17];

    int N = in_sizes[0] / 32;          // 32000
    int E = in_sizes[1];               // 384000
    int n_node = in_sizes[8] / 128;    // 1000
    int B = N / n_node;                // 32
    int T = 32;

    float* ws = (float*)d_ws;
    float* z      = ws;                                 // N*256
    float* asrc   = z + (size_t)N * 256;                // N*8
    float* adst   = asrc + (size_t)N * 8;               // N*8
    float* gatT   = adst + (size_t)N * 8;               // N*32
    float* P1     = gatT + (size_t)N * 32;              // T*B*128
    float* wc2f   = P1 + (size_t)T * B * 128;           // 8192 uint4 = 32768 f32
    float* wiff   = wc2f + 32768;                       // 2048 uint4 = 8192 f32
    float* w1ff   = wiff + 8192;                        // 512 uint4 = 2048 f32
    float* h2finT = w1ff + 2048;                        // 128*32
    float* wa     = h2finT + 128 * 32;                  // 512
    int* deg     = (int*)(wa + 512);                    // N
    int* cursor  = deg + N;                             // N
    int* rowptr  = cursor + N;                          // N+1
    int* csr_src = rowptr + N + 1;                      // E
    int* blksum  = csr_src + E;                         // 256
    int* blkoff  = blksum + 256;                        // 256
    float* Wt    = (float*)(((uintptr_t)(blkoff + 256) + 255) & ~(uintptr_t)255); // n_node*128

    uint4* wc2p = (uint4*)wc2f;
    uint4* wi2p = (uint4*)wiff;
    uint4* w1p  = (uint4*)w1ff;

    int nb = (N + 255) / 256;   // 125

    k_prep<<<171 + nb, 256, 0, stream>>>(W_ih1, Wt, n_node, W_hh2, W_ih2, W_hh1,
                                         wc2p, wi2p, w1p, W_gat, a_src, a_dst,
                                         wa, deg, N);
    k_hist<<<(E + 255) / 256, 256, 0, stream>>>(dst, deg, E);
    k_scan1<<<nb, 256, 0, stream>>>(deg, blksum, N);
    k_scan2<<<1, 256, 0, stream>>>(blksum, blkoff, nb);
    k_scan3<<<nb, 256, 0, stream>>>(deg, blkoff, rowptr, cursor, N, E);
    k_scatter<<<(E + 255) / 256, 256, 0, stream>>>(src, dst, cursor, csr_src, E);
    k_att<<<N / 32, 256, 0, stream>>>(x, wa, asrc, adst);
    k_gat<<<(N * 64 + 255) / 256, 256, 0, stream>>>(rowptr, csr_src, asrc, adst,
                                                    x, z, N);
    k_zw<<<2000, 256, 0, stream>>>(z, W_gat, b_gat, gatT, N, n_node);
    k_p1<<<B * 16, 256, 0, stream>>>(gatT, Wt, b_ih1, b_hh1, P1, n_node, B);
    k_lstm<<<B, 256, 0, stream>>>(P1, wc2p, wi2p, w1p, b_ih2, b_hh2, h2finT, B, T);
    k_fin<<<B * 8, 256, 0, stream>>>(h2finT, W_lin, b_lin, (float*)d_out, n_node, B);
}